// Round 2
// baseline (147.665 us; speedup 1.0000x reference)
//
#include <hip/hip_runtime.h>
#include <hip/hip_bf16.h>
#include <hip/hip_fp8.h>

typedef __attribute__((ext_vector_type(4))) int i32x4;
typedef __attribute__((ext_vector_type(8))) int i32x8;
typedef __attribute__((ext_vector_type(16))) float f32x16;

#define MARGIN 0.3f
#define BIGF 3.0e38f

#define VMCNT(n) asm volatile("s_waitcnt vmcnt(" #n ")" ::: "memory")

__device__ __forceinline__ void gl2lds16(const void* g, void* l) {
    __builtin_amdgcn_global_load_lds(
        (const __attribute__((address_space(1))) void*)g,
        (__attribute__((address_space(3))) void*)l,
        16, 0, 0);
}

__device__ __forceinline__ f32x16 mx_mfma(i32x8 a, i32x8 b, f32x16 c) {
    return __builtin_amdgcn_mfma_scale_f32_32x32x64_f8f6f4(
        a, b, c, 0 /*A fmt fp8*/, 0 /*B fmt fp8*/,
        0, 127 /*scale A = 2^0*/, 0, 127 /*scale B = 2^0*/);
}

// Swizzled fragment read: logical 16B chunks c0, c0+1 of one 128B LDS row.
__device__ __forceinline__ i32x8 ldfrag(const unsigned char* base, int c0, int e2) {
    i32x4 lo = *(const i32x4*)(base + (((c0)     ^ e2) << 4));
    i32x4 hi = *(const i32x4*)(base + (((c0 + 1) ^ e2) << 4));
    return __builtin_shufflevector(lo, hi, 0, 1, 2, 3, 4, 5, 6, 7);
}

// Wave-per-row convert: fp32 -> fp8 e4m3 (OCP) cast, fp32 row norm of the
// fp8-ROUNDED values (consistent with MFMA dots -> exact diagonal), init
// ap/an/cnt. 4 rows per 256-thread block. (R7/R8/R11-verified; UNCHANGED.)
__global__ __launch_bounds__(256) void convert_norm_kernel(
    const float* __restrict__ X, unsigned char* __restrict__ Xq,
    float* __restrict__ nrm, unsigned* __restrict__ ap,
    unsigned* __restrict__ an, unsigned* __restrict__ cnt, int K) {
    const int wave = threadIdx.x >> 6, lane = threadIdx.x & 63;
    const int row = blockIdx.x * 4 + wave;
    const float* xr = X + (size_t)row * K;
    unsigned char* xqr = Xq + (size_t)row * K;
    float s = 0.0f;
    for (int c = lane * 8; c < K; c += 64 * 8) {
        float4 v0 = *(const float4*)(xr + c);
        float4 v1 = *(const float4*)(xr + c + 4);
        float f[8] = {v0.x, v0.y, v0.z, v0.w, v1.x, v1.y, v1.z, v1.w};
        union { unsigned char b[8]; uint2 u; } p;
#pragma unroll
        for (int i = 0; i < 8; i++) {
            __hip_fp8_e4m3 q(f[i]);       // OCP e4m3, RNE+saturate
            p.b[i] = q.__x;
            float d = (float)q;           // decoded value
            s += d * d;
        }
        *(uint2*)(xqr + c) = p.u;
    }
    for (int off = 32; off > 0; off >>= 1) s += __shfl_xor(s, off, 64);
    if (lane == 0) {
        nrm[row] = s;
        ap[row] = 0u;           // dist_ap >= 0 always (self is a positive)
        an[row] = 0x7F800000u;  // +inf
        if (row == 0) *cnt = 0u;
    }
}

// 256x256-tile fp8-MX GEMM-reduce, 8 waves (2x4), wave tile 128x64 = 4x2
// subtiles of 32x32x64 mfma_scale. Grid = 256 blocks = exactly 1/CU.
// R1 post-mortem: bank conflicts -> 0 (swizzle works) but the iteration-
// boundary __syncthreads drained vmcnt(0), flushing the just-issued
// prefetch -> staging latency serially exposed every K-iter (the m218
// "drain-0 == no pipeline" regime, MfmaUtil 18%). This version is the
// T3+T4 schedule: 4 phases per K-tile (BK=128B), each phase =
// {issue 2 gl2lds of tile t+1 | ds_read this phase's frags | raw s_barrier
//  | setprio(1) 4x MFMA setprio(0) | raw s_barrier}. The ONLY vm wait per
// K-tile is a counted vmcnt(2) at phase 0 (tile t's 8 oldest loads done,
// tile t+1's 2 newest stay in flight across the boundary; m135 in-order
// vmcnt semantics). No __syncthreads in the main loop.
// Carried-over verified pieces: both-sides swizzle phys_chunk = logical ^
// (row&7) ^ ((row>>3)&3) (read key e2 = (m&7)^((m>>3)&3)), staging lane
// math (dest = uniform base + lane*16), operand layout (lane m = row,
// h = k-half), C/D map col=lane&31 row=(reg&3)+8*(reg>>2)+4*(lane>>5),
// monotone uint atomics, fused last-block loss.
__global__ __launch_bounds__(512, 2) void gemm_reduce_kernel(
    const unsigned char* __restrict__ Xq, const float* __restrict__ nrm,
    const int* __restrict__ Y, unsigned* __restrict__ ap,
    unsigned* __restrict__ an, unsigned* __restrict__ cnt,
    float* __restrict__ out, int N, int K) {
    __shared__ __align__(16) unsigned char sA[2][32768];  // 64 KB
    __shared__ __align__(16) unsigned char sB[2][32768];  // 64 KB
    __shared__ int sYr[256], sYc[256];
    __shared__ float sNr[256], sNc[256];
    __shared__ float redmax[4][256], redmin[4][256];      // [wc][row]
    __shared__ float lsum[8];
    __shared__ unsigned s_done;

    const int tid = threadIdx.x;
    const int wave = tid >> 6;
    const int lane = tid & 63;
    const int m = lane & 31;   // row within 32x32 subtile / col within subtile
    const int h = lane >> 5;   // k-half (inputs) / row-group (outputs)
    const int wr = wave >> 2;  // wave row (0..1): rows wr*128..+127
    const int wc = wave & 3;   // wave col (0..3): cols wc*64..+63

    const int NB = N >> 8;  // 16
    const int rowBase = (blockIdx.x / NB) << 8;
    const int colBase = (blockIdx.x % NB) << 8;

    if (tid < 256) {
        sYr[tid] = Y[rowBase + tid];
        sNr[tid] = nrm[rowBase + tid];
    } else {
        const int t = tid - 256;
        sYc[t] = Y[colBase + t];
        sNc[t] = nrm[colBase + t];
    }

    f32x16 acc[4][2];
#pragma unroll
    for (int si = 0; si < 4; si++)
#pragma unroll
        for (int sj = 0; sj < 2; sj++)
#pragma unroll
            for (int rr = 0; rr < 16; rr++) acc[si][sj][rr] = 0.0f;

    // Staging (R7-verified lane math + both-side swizzle): lane l -> LDS
    // row l>>3 of 8-row group g, phys chunk l&7; source logical chunk
    // (l&7)^(l>>3)^g so phys = logical ^ (row&7) ^ ((row>>3)&3).
    const int rsub = lane >> 3;
    const int jc = (lane & 7) ^ rsub;
    const unsigned char* gA = Xq + (size_t)(rowBase + wave * 32 + rsub) * K;
    const unsigned char* gB = Xq + (size_t)(colBase + wave * 32 + rsub) * K;
    const size_t g8 = (size_t)8 * K;  // 8 rows, bytes

    const int e2 = (m & 7) ^ ((m >> 3) & 3);  // read-side unswizzle key
    const int nit = K >> 7;                   // BK=128 bytes (16 iters)

    // Prologue: stage tile 0 into buffer 0 (8 gl2lds/wave; no drain here —
    // the first phase-0 counted vmcnt + barrier is the guard).
#pragma unroll
    for (int g = 0; g < 4; g++) {
        gl2lds16(gA + g * g8 + ((jc ^ g) << 4), &sA[0][wave * 4096 + g * 1024]);
        gl2lds16(gB + g * g8 + ((jc ^ g) << 4), &sB[0][wave * 4096 + g * 1024]);
    }

    int cur = 0;
    for (int it = 0; it < nit; ++it) {
        const unsigned char* cA = sA[cur];
        const unsigned char* cB = sB[cur];
        unsigned char* nA = sA[cur ^ 1] + wave * 4096;
        unsigned char* nB = sB[cur ^ 1] + wave * 4096;
        const bool pf = (it + 1 < nit);  // block-uniform
        const size_t go = (size_t)(it + 1) * 128;

        const unsigned char* rA = cA + (wr * 128 + m) * 128;  // + si*4096
        const unsigned char* rB = cB + (wc * 64 + m) * 128;   // + sj*4096

        i32x8 af0, af1, bf0, bf1;

        // ---- P0: vm-guard + (kstep0, si{0,1}) ----
        if (pf) {
            gl2lds16(gA + go + 0 * g8 + ((jc ^ 0) << 4), nA + 0 * 1024);
            gl2lds16(gA + go + 1 * g8 + ((jc ^ 1) << 4), nA + 1 * 1024);
            VMCNT(2);  // tile t's 8 oldest done; 2 newest stay in flight
        } else {
            VMCNT(0);  // last tile: nothing in flight behind it
        }
        __builtin_amdgcn_s_barrier();  // all waves' tile-t stage visible
        {
            const int c0 = h * 2;  // kstep 0
            af0 = ldfrag(rA + 0 * 4096, c0, e2);
            af1 = ldfrag(rA + 1 * 4096, c0, e2);
            bf0 = ldfrag(rB + 0 * 4096, c0, e2);
            bf1 = ldfrag(rB + 1 * 4096, c0, e2);
        }
        __builtin_amdgcn_s_setprio(1);
        acc[0][0] = mx_mfma(af0, bf0, acc[0][0]);
        acc[0][1] = mx_mfma(af0, bf1, acc[0][1]);
        acc[1][0] = mx_mfma(af1, bf0, acc[1][0]);
        acc[1][1] = mx_mfma(af1, bf1, acc[1][1]);
        __builtin_amdgcn_s_setprio(0);
        __builtin_amdgcn_s_barrier();

        // ---- P1: (kstep0, si{2,3}) ----
        if (pf) {
            gl2lds16(gA + go + 2 * g8 + ((jc ^ 2) << 4), nA + 2 * 1024);
            gl2lds16(gA + go + 3 * g8 + ((jc ^ 3) << 4), nA + 3 * 1024);
        }
        {
            const int c0 = h * 2;
            af0 = ldfrag(rA + 2 * 4096, c0, e2);
            af1 = ldfrag(rA + 3 * 4096, c0, e2);
        }
        __builtin_amdgcn_s_barrier();
        __builtin_amdgcn_s_setprio(1);
        acc[2][0] = mx_mfma(af0, bf0, acc[2][0]);
        acc[2][1] = mx_mfma(af0, bf1, acc[2][1]);
        acc[3][0] = mx_mfma(af1, bf0, acc[3][0]);
        acc[3][1] = mx_mfma(af1, bf1, acc[3][1]);
        __builtin_amdgcn_s_setprio(0);
        __builtin_amdgcn_s_barrier();

        // ---- P2: (kstep1, si{0,1}) ----
        if (pf) {
            gl2lds16(gB + go + 0 * g8 + ((jc ^ 0) << 4), nB + 0 * 1024);
            gl2lds16(gB + go + 1 * g8 + ((jc ^ 1) << 4), nB + 1 * 1024);
        }
        {
            const int c0 = 4 + h * 2;  // kstep 1
            af0 = ldfrag(rA + 0 * 4096, c0, e2);
            af1 = ldfrag(rA + 1 * 4096, c0, e2);
            bf0 = ldfrag(rB + 0 * 4096, c0, e2);
            bf1 = ldfrag(rB + 1 * 4096, c0, e2);
        }
        __builtin_amdgcn_s_barrier();
        __builtin_amdgcn_s_setprio(1);
        acc[0][0] = mx_mfma(af0, bf0, acc[0][0]);
        acc[0][1] = mx_mfma(af0, bf1, acc[0][1]);
        acc[1][0] = mx_mfma(af1, bf0, acc[1][0]);
        acc[1][1] = mx_mfma(af1, bf1, acc[1][1]);
        __builtin_amdgcn_s_setprio(0);
        __builtin_amdgcn_s_barrier();

        // ---- P3: (kstep1, si{2,3}) ----
        if (pf) {
            gl2lds16(gB + go + 2 * g8 + ((jc ^ 2) << 4), nB + 2 * 1024);
            gl2lds16(gB + go + 3 * g8 + ((jc ^ 3) << 4), nB + 3 * 1024);
        }
        {
            const int c0 = 4 + h * 2;
            af0 = ldfrag(rA + 2 * 4096, c0, e2);
            af1 = ldfrag(rA + 3 * 4096, c0, e2);
        }
        __builtin_amdgcn_s_barrier();
        __builtin_amdgcn_s_setprio(1);
        acc[2][0] = mx_mfma(af0, bf0, acc[2][0]);
        acc[2][1] = mx_mfma(af0, bf1, acc[2][1]);
        acc[3][0] = mx_mfma(af1, bf0, acc[3][0]);
        acc[3][1] = mx_mfma(af1, bf1, acc[3][1]);
        __builtin_amdgcn_s_setprio(0);
        __builtin_amdgcn_s_barrier();

        cur ^= 1;
    }

    // Epilogue: ROW-side reduction (full G). C/D: col (within subtile) = m,
    // row within wave's 128 rows = si*32 + (reg&3) + 8*(reg>>2) + 4*h.
#pragma unroll
    for (int si = 0; si < 4; si++)
#pragma unroll
        for (int reg = 0; reg < 16; reg++) {
            const int row128 = si * 32 + (reg & 3) + 8 * (reg >> 2) + 4 * h;
            const int rIdx = wr * 128 + row128;  // row within block tile
            const int yr = sYr[rIdx];
            const float nr = sNr[rIdx];
            float dp = -1.0f, dn = BIGF;
#pragma unroll
            for (int sj = 0; sj < 2; sj++) {
                const int cIdx = wc * 64 + sj * 32 + m;
                float d2 = nr + sNc[cIdx] - 2.0f * acc[si][sj][reg];
                float d = sqrtf(fmaxf(d2, 0.0f));
                bool same = (yr == sYc[cIdx]);
                dp = fmaxf(dp, same ? d : -1.0f);
                dn = fminf(dn, same ? BIGF : d);
            }
            // Reduce over the 32 col-lanes (offsets 1..16 keep h fixed).
            for (int off = 1; off < 32; off <<= 1) {
                dp = fmaxf(dp, __shfl_xor(dp, off, 64));
                dn = fminf(dn, __shfl_xor(dn, off, 64));
            }
            if (m == 0) {  // lanes 0 (h=0) and 32 (h=1): disjoint rows
                redmax[wc][rIdx] = dp;
                redmin[wc][rIdx] = dn;
            }
        }
    __syncthreads();

    // Combine the 4 wc waves per row; one atomic pair per row.
    // Non-negative floats: uint cmp == float cmp; clamp max to 0 (true
    // dist_ap >= 0 via the diagonal self-pair).
    if (tid < 256) {
        float mx = fmaxf(fmaxf(redmax[0][tid], redmax[1][tid]),
                         fmaxf(redmax[2][tid], redmax[3][tid]));
        float mn = fminf(fminf(redmin[0][tid], redmin[1][tid]),
                         fminf(redmin[2][tid], redmin[3][tid]));
        atomicMax(&ap[rowBase + tid], __float_as_uint(fmaxf(mx, 0.0f)));
        atomicMin(&an[rowBase + tid], __float_as_uint(mn));
    }

    // Last block computes the loss (release fence before counter increment;
    // acquire fence + agent-scope atomic loads in the last block).
    __syncthreads();
    if (tid == 0) {
        __threadfence();
        s_done = atomicAdd(cnt, 1u);
    }
    __syncthreads();
    if (s_done == gridDim.x - 1) {
        __threadfence();
        float s = 0.0f;
        for (int i = tid; i < N; i += 512) {
            unsigned ua = __hip_atomic_load(&ap[i], __ATOMIC_RELAXED,
                                            __HIP_MEMORY_SCOPE_AGENT);
            unsigned ub = __hip_atomic_load(&an[i], __ATOMIC_RELAXED,
                                            __HIP_MEMORY_SCOPE_AGENT);
            s += fmaxf(__uint_as_float(ua) - __uint_as_float(ub) + MARGIN, 0.0f);
        }
        for (int off = 32; off > 0; off >>= 1) s += __shfl_xor(s, off, 64);
        if (lane == 0) lsum[wave] = s;
        __syncthreads();
        if (tid == 0) {
            float t = 0.0f;
#pragma unroll
            for (int w = 0; w < 8; w++) t += lsum[w];
            out[0] = t / (float)N;
        }
    }
}

extern "C" void kernel_launch(void* const* d_in, const int* in_sizes, int n_in,
                              void* d_out, int out_size, void* d_ws, size_t ws_size,
                              hipStream_t stream) {
    const float* X = (const float*)d_in[0];
    const int* Y = (const int*)d_in[1];
    float* out = (float*)d_out;
    const int N = in_sizes[1];          // 4096
    const int K = in_sizes[0] / N;      // 2048

    char* ws = (char*)d_ws;
    unsigned char* Xq = (unsigned char*)ws;                         // N*K bytes
    float* nrm = (float*)(ws + (size_t)N * K);
    unsigned* ap = (unsigned*)((char*)nrm + (size_t)N * 4);
    unsigned* an = (unsigned*)((char*)ap + (size_t)N * 4);
    unsigned* cnt = (unsigned*)((char*)an + (size_t)N * 4);

    convert_norm_kernel<<<N / 4, 256, 0, stream>>>(X, Xq, nrm, ap, an, cnt, K);
    const int NB = N / 256;
    gemm_reduce_kernel<<<NB * NB, 512, 0, stream>>>(Xq, nrm, Y, ap, an, cnt,
                                                    out, N, K);
}

// Round 3
// 132.916 us; speedup vs baseline: 1.1110x; 1.1110x over previous
//
#include <hip/hip_runtime.h>
#include <hip/hip_bf16.h>
#include <hip/hip_fp8.h>

typedef __attribute__((ext_vector_type(4))) int i32x4;
typedef __attribute__((ext_vector_type(8))) int i32x8;
typedef __attribute__((ext_vector_type(16))) float f32x16;

#define MARGIN 0.3f
#define BIGF 3.0e38f

__device__ __forceinline__ void gl2lds16(const void* g, void* l) {
    __builtin_amdgcn_global_load_lds(
        (const __attribute__((address_space(1))) void*)g,
        (__attribute__((address_space(3))) void*)l,
        16, 0, 0);
}

// Wave-per-row convert: fp32 -> fp8 e4m3 (OCP) cast, fp32 row norm of the
// fp8-ROUNDED values (consistent with MFMA dots -> exact diagonal), init
// ap/an/cnt. 4 rows per 256-thread block. (R7/R8/R11-verified; UNCHANGED.)
__global__ __launch_bounds__(256) void convert_norm_kernel(
    const float* __restrict__ X, unsigned char* __restrict__ Xq,
    float* __restrict__ nrm, unsigned* __restrict__ ap,
    unsigned* __restrict__ an, unsigned* __restrict__ cnt, int K) {
    const int wave = threadIdx.x >> 6, lane = threadIdx.x & 63;
    const int row = blockIdx.x * 4 + wave;
    const float* xr = X + (size_t)row * K;
    unsigned char* xqr = Xq + (size_t)row * K;
    float s = 0.0f;
    for (int c = lane * 8; c < K; c += 64 * 8) {
        float4 v0 = *(const float4*)(xr + c);
        float4 v1 = *(const float4*)(xr + c + 4);
        float f[8] = {v0.x, v0.y, v0.z, v0.w, v1.x, v1.y, v1.z, v1.w};
        union { unsigned char b[8]; uint2 u; } p;
#pragma unroll
        for (int i = 0; i < 8; i++) {
            __hip_fp8_e4m3 q(f[i]);       // OCP e4m3, RNE+saturate
            p.b[i] = q.__x;
            float d = (float)q;           // decoded value
            s += d * d;
        }
        *(uint2*)(xqr + c) = p.u;
    }
    for (int off = 32; off > 0; off >>= 1) s += __shfl_xor(s, off, 64);
    if (lane == 0) {
        nrm[row] = s;
        ap[row] = 0u;           // dist_ap >= 0 always (self is a positive)
        an[row] = 0x7F800000u;  // +inf
        if (row == 0) *cnt = 0u;
    }
}

// FULL-SQUARE fp8-MX GEMM-reduce, R0 geometry restored: 128x128 tiles ->
// EXACTLY 1024 blocks = 4.0 blocks/CU. R1/R2 post-mortem: the 256^2
// deep-pipeline variants (1 block/CU, 8 lockstep waves) were SLOWER (72,
// 79 us vs 65) — per-K-tile cost was nearly invariant across three sync
// structures, i.e. source-level pipelining bought nothing (m114/m131-m140:
// implicit cross-block wave overlap at 4 blocks/CU already captures it).
// The one measured win from R1/R2 is kept: the double-XOR LDS swizzle
// (SQ_LDS_BANK_CONFLICT 4.19M -> 0). R0's single-XOR key (row&7 only)
// left lanes {m, m+8, m+16, m+24} on the same 16B chunk column -> 8-way
// bank conflict on every ds_read_b128 — the LDS pipe is the shared per-CU
// resource all 4 resident blocks contend for, so conflicts serialized the
// whole CU.
// Swizzle (R1/R2-verified, both sides): phys_chunk = logical ^ (row&7) ^
// ((row>>3)&3). Staging: lane l -> LDS row l>>3 of 8-row group g, phys
// chunk l&7, source logical chunk (l&7)^(l>>3)^g (row&7 = l>>3, row-group
// bits = g since wave regions are 32-row-aligned). Read key: row = wr*64 +
// si*32 + m -> e2 = (m&7) ^ ((m>>3)&3).
// All other pieces R0-verified and unchanged: 4 waves (2x2), wave tile
// 64x64 = 2x2 subtiles of 32x32x64 mfma_scale (unit scales 0x7F), BK=128,
// 16 iters, C/D map col=lane&31 row=(reg&3)+8*(reg>>2)+4*(lane>>5),
// monotone uint atomics, fused last-block loss, __launch_bounds__(256,4).
__global__ __launch_bounds__(256, 4) void gemm_reduce_kernel(
    const unsigned char* __restrict__ Xq, const float* __restrict__ nrm,
    const int* __restrict__ Y, unsigned* __restrict__ ap,
    unsigned* __restrict__ an, unsigned* __restrict__ cnt,
    float* __restrict__ out, int N, int K) {
    __shared__ __align__(16) unsigned char sA[128 * 128];  // 16 KB
    __shared__ __align__(16) unsigned char sB[128 * 128];  // 16 KB
    __shared__ int sYr[128], sYc[128];
    __shared__ float sNr[128], sNc[128];
    __shared__ float redmax[4][64], redmin[4][64];
    __shared__ float lsum[4];
    __shared__ unsigned s_done;

    const int tid = threadIdx.x;
    const int wave = tid >> 6;
    const int lane = tid & 63;
    const int m = lane & 31;   // row within 32x32 subtile / col within subtile
    const int h = lane >> 5;   // k-half (inputs) / row-group (outputs)
    const int wr = wave >> 1;  // wave row (0..1): rows wr*64..+63
    const int wc = wave & 1;   // wave col (0..1): cols wc*64..+63

    const int NB = N >> 7;  // 32
    const int rowBase = (blockIdx.x >> 5) * 128;
    const int colBase = (blockIdx.x & (NB - 1)) * 128;

    if (tid < 128) {
        sYr[tid] = Y[rowBase + tid];
        sNr[tid] = nrm[rowBase + tid];
    } else {
        int t = tid - 128;
        sYc[t] = Y[colBase + t];
        sNc[t] = nrm[colBase + t];
    }

    f32x16 acc[2][2];
#pragma unroll
    for (int si = 0; si < 2; si++)
#pragma unroll
        for (int sj = 0; sj < 2; sj++)
#pragma unroll
            for (int rr = 0; rr < 16; rr++) acc[si][sj][rr] = 0.0f;

    // Staging (R7-verified lane math + R1/R2-verified double-XOR swizzle):
    // lane l covers LDS row l>>3 of an 8-row group g, physical 16B chunk
    // l&7, fetching LOGICAL chunk (l&7)^(l>>3)^g so phys = logical ^
    // (row&7) ^ ((row>>3)&3). Each wave stages its own 32 rows of A and of
    // B (4 gl2lds each, 1 KB per gl2lds).
    const int rsub = lane >> 3;
    const int jc = (lane & 7) ^ rsub;
    const unsigned char* gA = Xq + (size_t)(rowBase + wave * 32 + rsub) * K;
    const unsigned char* gB = Xq + (size_t)(colBase + wave * 32 + rsub) * K;
    unsigned char* lA = sA + wave * 4096;  // 32 rows * 128 B
    unsigned char* lB = sB + wave * 4096;
    const size_t g8 = (size_t)8 * K;  // 8 rows, bytes

    const int e2 = (m & 7) ^ ((m >> 3) & 3);  // read-side unswizzle key
    const int nit = K >> 7;                   // BK=128 (16 iters at K=2048)

    for (int it = 0; it < nit; it++) {
        const size_t go = (size_t)it * 128;  // 128 k-elems * 1 B
#pragma unroll
        for (int g = 0; g < 4; g++) {
            gl2lds16(gA + go + g * g8 + ((jc ^ g) << 4), lA + g * 1024);
            gl2lds16(gB + go + g * g8 + ((jc ^ g) << 4), lB + g * 1024);
        }
        __syncthreads();  // drains vmcnt for gl2lds

#pragma unroll
        for (int s = 0; s < 2; s++) {      // two k64 steps per BK=128
            const int c0 = s * 4 + h * 2;  // logical 16B chunk of this k-half
            i32x8 af[2], bf[2];
#pragma unroll
            for (int si = 0; si < 2; si++) {
                const unsigned char* base = sA + (wr * 64 + si * 32 + m) * 128;
                i32x4 lo = *(const i32x4*)(base + (((c0) ^ e2) << 4));
                i32x4 hi = *(const i32x4*)(base + (((c0 + 1) ^ e2) << 4));
                af[si] = __builtin_shufflevector(lo, hi, 0, 1, 2, 3, 4, 5, 6, 7);
            }
#pragma unroll
            for (int sj = 0; sj < 2; sj++) {
                const unsigned char* base = sB + (wc * 64 + sj * 32 + m) * 128;
                i32x4 lo = *(const i32x4*)(base + (((c0) ^ e2) << 4));
                i32x4 hi = *(const i32x4*)(base + (((c0 + 1) ^ e2) << 4));
                bf[sj] = __builtin_shufflevector(lo, hi, 0, 1, 2, 3, 4, 5, 6, 7);
            }
#pragma unroll
            for (int si = 0; si < 2; si++)
#pragma unroll
                for (int sj = 0; sj < 2; sj++)
                    acc[si][sj] = __builtin_amdgcn_mfma_scale_f32_32x32x64_f8f6f4(
                        af[si], bf[sj], acc[si][sj], 0 /*A fmt fp8*/,
                        0 /*B fmt fp8*/, 0, 127 /*scale A = 2^0*/,
                        0, 127 /*scale B = 2^0*/);
        }
        __syncthreads();  // protect single buffer before restage
    }

    // Epilogue: ROW-side only (full G). C/D: col (within subtile) = m,
    // row64 (within wave's 64 rows) = si*32 + (reg&3) + 8*(reg>>2) + 4*h.
#pragma unroll
    for (int si = 0; si < 2; si++)
#pragma unroll
        for (int reg = 0; reg < 16; reg++) {
            const int row64 = si * 32 + (reg & 3) + 8 * (reg >> 2) + 4 * h;
            const int rIdx = wr * 64 + row64;  // row within block tile
            const int yr = sYr[rIdx];
            const float nr = sNr[rIdx];
            float dp = -1.0f, dn = BIGF;
#pragma unroll
            for (int sj = 0; sj < 2; sj++) {
                const int cIdx = wc * 64 + sj * 32 + m;
                float d2 = nr + sNc[cIdx] - 2.0f * acc[si][sj][reg];
                float d = sqrtf(fmaxf(d2, 0.0f));
                bool same = (yr == sYc[cIdx]);
                dp = fmaxf(dp, same ? d : -1.0f);
                dn = fminf(dn, same ? BIGF : d);
            }
            // Reduce over the 32 col-lanes (offsets 1..16 keep h fixed).
            for (int off = 1; off < 32; off <<= 1) {
                dp = fmaxf(dp, __shfl_xor(dp, off, 64));
                dn = fminf(dn, __shfl_xor(dn, off, 64));
            }
            if (m == 0) {  // lanes 0 (h=0) and 32 (h=1): disjoint row64 sets
                redmax[wave][row64] = dp;
                redmin[wave][row64] = dn;
            }
        }
    __syncthreads();

    // Combine the two wc waves of each wr half; one atomic pair per row.
    // Non-negative floats: uint cmp == float cmp; clamp max to 0 (true
    // dist_ap >= 0 via the diagonal self-pair).
    if (tid < 128) {
        const int wr2 = tid >> 6, r64 = tid & 63;
        float mx = fmaxf(redmax[wr2 * 2][r64], redmax[wr2 * 2 + 1][r64]);
        float mn = fminf(redmin[wr2 * 2][r64], redmin[wr2 * 2 + 1][r64]);
        atomicMax(&ap[rowBase + tid], __float_as_uint(fmaxf(mx, 0.0f)));
        atomicMin(&an[rowBase + tid], __float_as_uint(mn));
    }

    // Last block computes the loss (release fence before counter increment;
    // acquire fence + agent-scope atomic loads in the last block).
    __syncthreads();
    if (tid == 0) {
        __threadfence();
        s_done = atomicAdd(cnt, 1u);
    }
    __syncthreads();
    if (s_done == gridDim.x - 1) {
        __threadfence();
        float s = 0.0f;
        for (int i = tid; i < N; i += 256) {
            unsigned ua = __hip_atomic_load(&ap[i], __ATOMIC_RELAXED,
                                            __HIP_MEMORY_SCOPE_AGENT);
            unsigned ub = __hip_atomic_load(&an[i], __ATOMIC_RELAXED,
                                            __HIP_MEMORY_SCOPE_AGENT);
            s += fmaxf(__uint_as_float(ua) - __uint_as_float(ub) + MARGIN, 0.0f);
        }
        for (int off = 32; off > 0; off >>= 1) s += __shfl_xor(s, off, 64);
        if (lane == 0) lsum[wave] = s;
        __syncthreads();
        if (tid == 0)
            out[0] = (lsum[0] + lsum[1] + lsum[2] + lsum[3]) / (float)N;
    }
}

extern "C" void kernel_launch(void* const* d_in, const int* in_sizes, int n_in,
                              void* d_out, int out_size, void* d_ws, size_t ws_size,
                              hipStream_t stream) {
    const float* X = (const float*)d_in[0];
    const int* Y = (const int*)d_in[1];
    float* out = (float*)d_out;
    const int N = in_sizes[1];          // 4096
    const int K = in_sizes[0] / N;      // 2048

    char* ws = (char*)d_ws;
    unsigned char* Xq = (unsigned char*)ws;                         // N*K bytes
    float* nrm = (float*)(ws + (size_t)N * K);
    unsigned* ap = (unsigned*)((char*)nrm + (size_t)N * 4);
    unsigned* an = (unsigned*)((char*)ap + (size_t)N * 4);
    unsigned* cnt = (unsigned*)((char*)an + (size_t)N * 4);

    convert_norm_kernel<<<N / 4, 256, 0, stream>>>(X, Xq, nrm, ap, an, cnt, K);
    const int NB = N / 128;
    gemm_reduce_kernel<<<NB * NB, 256, 0, stream>>>(Xq, nrm, Y, ap, an, cnt,
                                                    out, N, K);
}